// Round 12
// baseline (50.802 us; speedup 1.0000x reference)
//
#include <hip/hip_runtime.h>

#define FEAT 64

typedef float vfloat2 __attribute__((ext_vector_type(2)));
typedef float vfloat4 __attribute__((ext_vector_type(4)));

// Fused prep: feat -> fp8 table + out[:,0:64] f32 (NT); CSR rowptr via
// adjacent-pair scan of the sorted edge_dst.
__global__ void prep(const float* __restrict__ feat,
                     const int* __restrict__ edge_dst,
                     unsigned char* __restrict__ ftab,    // [N][64] fp8
                     int* __restrict__ row_start,         // [N+1]
                     float* __restrict__ out, int N, int E) {
    int t = blockIdx.x * blockDim.x + threadIdx.x;
    if (t < N * 8) {
        int n = t >> 3, q = t & 7;
        const float* srcp = feat + (size_t)n * FEAT + q * 8;
        vfloat4 a = __builtin_nontemporal_load((const vfloat4*)srcp);
        vfloat4 b = __builtin_nontemporal_load((const vfloat4*)(srcp + 4));
        int w0 = __builtin_amdgcn_cvt_pk_fp8_f32(a.x, a.y, 0, false);
        w0     = __builtin_amdgcn_cvt_pk_fp8_f32(a.z, a.w, w0, true);
        int w1 = __builtin_amdgcn_cvt_pk_fp8_f32(b.x, b.y, 0, false);
        w1     = __builtin_amdgcn_cvt_pk_fp8_f32(b.z, b.w, w1, true);
        uint2 o; o.x = (unsigned)w0; o.y = (unsigned)w1;
        *(uint2*)(ftab + (size_t)n * FEAT + q * 8) = o;
        float* orow = out + (size_t)n * 256 + q * 8;
        __builtin_nontemporal_store(a, (vfloat4*)orow);
        __builtin_nontemporal_store(b, (vfloat4*)(orow + 4));
    }
    if (t <= E) {
        int a = (t == 0) ? -1 : edge_dst[t - 1];
        int b = (t == E) ? N  : edge_dst[t];
        for (int n = a + 1; n <= b; ++n) row_start[n] = t;
    }
}

// Decode a uint2 (8 fp8) into 4 packed vfloat2 accumulators.
#define ACCP(P)                                                     \
    {                                                               \
        a0 += __builtin_amdgcn_cvt_pk_f32_fp8((int)(P).x, false);   \
        a1 += __builtin_amdgcn_cvt_pk_f32_fp8((int)(P).x, true);    \
        a2 += __builtin_amdgcn_cvt_pk_f32_fp8((int)(P).y, false);   \
        a3 += __builtin_amdgcn_cvt_pk_f32_fp8((int)(P).y, true);    \
    }

// One wave per 2 contiguous nodes. The pair's edge indices live in ONE
// contiguous edge_src window [rs0, rs2) — loaded with a single coalesced
// per-lane load (64 indices) and distributed to slots via shfl. All 8
// row-gathers (8B fp8) for both nodes issued before any decode.
// eg = lane>>3 (edge slot group), fq = lane&7 (8B = 8 fp8 dims).
template<int IS_HOP2>
__global__ void __launch_bounds__(256) hop(
        const unsigned char* __restrict__ table,
        const int* __restrict__ edge_src,
        const int* __restrict__ row_start,
        float* __restrict__ out,
        unsigned char* __restrict__ agg1t,
        int N, int E) {
    int wid = (blockIdx.x * blockDim.x + threadIdx.x) >> 6;
    int lane = threadIdx.x & 63;
    int eg = lane >> 3;
    int fq = lane & 7;
    int base = wid * 2;
    if (base >= N) return;

    int rs0 = row_start[base];
    int rs1 = row_start[base + 1];
    int i2 = (base + 2 <= N) ? (base + 2) : N;
    int rs2 = row_start[i2];
    bool hasB = (base + 1) < N;
    int degA = rs1 - rs0;
    int degB = rs2 - rs1;

    // one coalesced load of the pair's edge-index window
    int si = rs0 + lane;
    int ci = (si < rs2) ? si : ((rs2 > rs0) ? rs2 - 1 : ((rs0 < E) ? rs0 : E - 1));
    int espan = edge_src[ci];

    int lastA = (degA > 0) ? ((degA - 1 < 31) ? degA - 1 : 31) : 0;
    int lastB = (degB > 0) ? ((degB - 1 < 31) ? degB - 1 : 31) : 0;
    bool bSpan = (degA <= 32);        // B's slots reachable within the 64-lane span

    bool vA[4], vB[4];
    int idxA[4], idxB[4];
    #pragma unroll
    for (int b = 0; b < 4; ++b) {
        int s = eg + 8 * b;           // slot 0..31
        vA[b] = s < degA;
        int laA = vA[b] ? s : lastA;
        idxA[b] = __shfl(espan, laA, 64);
        vB[b] = hasB && (s < degB) && (s < 32);
        int slotB = vB[b] ? s : lastB;
        if (bSpan) {
            idxB[b] = __shfl(espan, degA + slotB, 64);
        } else {                      // rare: degA>32, B beyond span
            int j = rs1 + slotB;
            idxB[b] = edge_src[(j < E) ? j : E - 1];
        }
    }

    uint2 pA[4], pB[4];
    #pragma unroll
    for (int b = 0; b < 4; ++b)
        pA[b] = *(const uint2*)(table + (size_t)idxA[b] * FEAT + fq * 8);
    #pragma unroll
    for (int b = 0; b < 4; ++b)
        pB[b] = *(const uint2*)(table + (size_t)idxB[b] * FEAT + fq * 8);

    // ---- node A ----
    {
        vfloat2 a0 = {0.f,0.f}, a1 = {0.f,0.f}, a2 = {0.f,0.f}, a3 = {0.f,0.f};
        #pragma unroll
        for (int b = 0; b < 4; ++b) {
            uint2 p = pA[b];
            if (!vA[b]) { p.x = 0u; p.y = 0u; }
            ACCP(p);
        }
        for (int i = rs0 + 32 + eg; i < rs1; i += 8) {   // rare deg>32 tail
            int j = edge_src[i];
            uint2 p = *(const uint2*)(table + (size_t)j * FEAT + fq * 8);
            ACCP(p);
        }
        #pragma unroll
        for (int m = 8; m <= 32; m <<= 1) {
            a0.x += __shfl_xor(a0.x, m, 64); a0.y += __shfl_xor(a0.y, m, 64);
            a1.x += __shfl_xor(a1.x, m, 64); a1.y += __shfl_xor(a1.y, m, 64);
            a2.x += __shfl_xor(a2.x, m, 64); a2.y += __shfl_xor(a2.y, m, 64);
            a3.x += __shfl_xor(a3.x, m, 64); a3.y += __shfl_xor(a3.y, m, 64);
        }
        float inv = 1.0f / (float)(degA > 0 ? degA : 1);
        a0 *= inv; a1 *= inv; a2 *= inv; a3 *= inv;

        float* orow = out + (size_t)base * 256;
        vfloat4 v0 = {a0.x, a0.y, a1.x, a1.y};
        vfloat4 v1 = {a2.x, a2.y, a3.x, a3.y};
        if (IS_HOP2) {
            if (eg == 0) {
                __builtin_nontemporal_store(v0, (vfloat4*)(orow + 192 + fq * 8));
                __builtin_nontemporal_store(v1, (vfloat4*)(orow + 192 + fq * 8 + 4));
            }
        } else {
            if (eg == 0) {
                __builtin_nontemporal_store(v0, (vfloat4*)(orow + 64 + fq * 8));
                __builtin_nontemporal_store(v1, (vfloat4*)(orow + 64 + fq * 8 + 4));
            } else if (eg == 1) {
                __builtin_nontemporal_store(v0, (vfloat4*)(orow + 128 + fq * 8));
                __builtin_nontemporal_store(v1, (vfloat4*)(orow + 128 + fq * 8 + 4));
            } else if (eg == 2) {
                int w0 = __builtin_amdgcn_cvt_pk_fp8_f32(a0.x, a0.y, 0, false);
                w0     = __builtin_amdgcn_cvt_pk_fp8_f32(a1.x, a1.y, w0, true);
                int w1 = __builtin_amdgcn_cvt_pk_fp8_f32(a2.x, a2.y, 0, false);
                w1     = __builtin_amdgcn_cvt_pk_fp8_f32(a3.x, a3.y, w1, true);
                uint2 pk; pk.x = (unsigned)w0; pk.y = (unsigned)w1;
                *(uint2*)(agg1t + (size_t)base * FEAT + fq * 8) = pk;
            }
        }
    }

    // ---- node B ----
    if (hasB) {
        vfloat2 a0 = {0.f,0.f}, a1 = {0.f,0.f}, a2 = {0.f,0.f}, a3 = {0.f,0.f};
        #pragma unroll
        for (int b = 0; b < 4; ++b) {
            uint2 p = pB[b];
            if (!vB[b]) { p.x = 0u; p.y = 0u; }
            ACCP(p);
        }
        for (int i = rs1 + 32 + eg; i < rs2; i += 8) {   // rare deg>32 tail
            int j = edge_src[i];
            uint2 p = *(const uint2*)(table + (size_t)j * FEAT + fq * 8);
            ACCP(p);
        }
        #pragma unroll
        for (int m = 8; m <= 32; m <<= 1) {
            a0.x += __shfl_xor(a0.x, m, 64); a0.y += __shfl_xor(a0.y, m, 64);
            a1.x += __shfl_xor(a1.x, m, 64); a1.y += __shfl_xor(a1.y, m, 64);
            a2.x += __shfl_xor(a2.x, m, 64); a2.y += __shfl_xor(a2.y, m, 64);
            a3.x += __shfl_xor(a3.x, m, 64); a3.y += __shfl_xor(a3.y, m, 64);
        }
        float inv = 1.0f / (float)(degB > 0 ? degB : 1);
        a0 *= inv; a1 *= inv; a2 *= inv; a3 *= inv;

        float* orow = out + (size_t)(base + 1) * 256;
        vfloat4 v0 = {a0.x, a0.y, a1.x, a1.y};
        vfloat4 v1 = {a2.x, a2.y, a3.x, a3.y};
        if (IS_HOP2) {
            if (eg == 0) {
                __builtin_nontemporal_store(v0, (vfloat4*)(orow + 192 + fq * 8));
                __builtin_nontemporal_store(v1, (vfloat4*)(orow + 192 + fq * 8 + 4));
            }
        } else {
            if (eg == 0) {
                __builtin_nontemporal_store(v0, (vfloat4*)(orow + 64 + fq * 8));
                __builtin_nontemporal_store(v1, (vfloat4*)(orow + 64 + fq * 8 + 4));
            } else if (eg == 1) {
                __builtin_nontemporal_store(v0, (vfloat4*)(orow + 128 + fq * 8));
                __builtin_nontemporal_store(v1, (vfloat4*)(orow + 128 + fq * 8 + 4));
            } else if (eg == 2) {
                int w0 = __builtin_amdgcn_cvt_pk_fp8_f32(a0.x, a0.y, 0, false);
                w0     = __builtin_amdgcn_cvt_pk_fp8_f32(a1.x, a1.y, w0, true);
                int w1 = __builtin_amdgcn_cvt_pk_fp8_f32(a2.x, a2.y, 0, false);
                w1     = __builtin_amdgcn_cvt_pk_fp8_f32(a3.x, a3.y, w1, true);
                uint2 pk; pk.x = (unsigned)w0; pk.y = (unsigned)w1;
                *(uint2*)(agg1t + (size_t)(base + 1) * FEAT + fq * 8) = pk;
            }
        }
    }
}

extern "C" void kernel_launch(void* const* d_in, const int* in_sizes, int n_in,
                              void* d_out, int out_size, void* d_ws, size_t ws_size,
                              hipStream_t stream) {
    const float* feat     = (const float*)d_in[0];
    const int*   edge_src = (const int*)d_in[1];
    const int*   edge_dst = (const int*)d_in[2];
    float*       out      = (float*)d_out;

    int N = in_sizes[0] / FEAT;
    int E = in_sizes[1];

    // ws: ftab [N*64] fp8, agg1t [N*64] fp8, row_start [N+1] int
    unsigned char* ftab  = (unsigned char*)d_ws;
    unsigned char* agg1t = ftab + (size_t)N * FEAT;
    int* row_start       = (int*)(agg1t + (size_t)N * FEAT);

    int prep_blocks = (E + 1 + 255) / 256;           // covers t<=E and t<N*8
    prep<<<prep_blocks, 256, 0, stream>>>(feat, edge_dst, ftab, row_start, out, N, E);

    int waves  = (N + 1) / 2;
    int blocks = (waves + 3) / 4;                    // 4 waves per 256-thread block
    hop<0><<<blocks, 256, 0, stream>>>(ftab,  edge_src, row_start, out, agg1t, N, E);
    hop<1><<<blocks, 256, 0, stream>>>(agg1t, edge_src, row_start, out, agg1t, N, E);
}

// Round 13
// 47.375 us; speedup vs baseline: 1.0723x; 1.0723x over previous
//
#include <hip/hip_runtime.h>

#define FEAT 64

typedef float vfloat2 __attribute__((ext_vector_type(2)));
typedef float vfloat4 __attribute__((ext_vector_type(4)));

// Decode a uint2 (8 fp8 e4m3) into 4 packed vfloat2 accumulators (v_pk_add_f32).
#define ACCP(P)                                                     \
    {                                                               \
        a0 += __builtin_amdgcn_cvt_pk_f32_fp8((int)(P).x, false);   \
        a1 += __builtin_amdgcn_cvt_pk_f32_fp8((int)(P).x, true);    \
        a2 += __builtin_amdgcn_cvt_pk_f32_fp8((int)(P).y, false);   \
        a3 += __builtin_amdgcn_cvt_pk_f32_fp8((int)(P).y, true);    \
    }

// Fused prep: feat -> fp8 table + out[:,0:64] f32 (NT); CSR rowptr via
// adjacent-pair scan of the sorted edge_dst (coalesced, no binary search).
__global__ void prep(const float* __restrict__ feat,
                     const int* __restrict__ edge_dst,
                     unsigned char* __restrict__ ftab,    // [N][64] fp8
                     int* __restrict__ row_start,         // [N+1]
                     float* __restrict__ out, int N, int E) {
    int t = blockIdx.x * blockDim.x + threadIdx.x;
    if (t < N * 8) {
        int n = t >> 3, q = t & 7;
        const float* srcp = feat + (size_t)n * FEAT + q * 8;
        vfloat4 a = __builtin_nontemporal_load((const vfloat4*)srcp);
        vfloat4 b = __builtin_nontemporal_load((const vfloat4*)(srcp + 4));
        int w0 = __builtin_amdgcn_cvt_pk_fp8_f32(a.x, a.y, 0, false);
        w0     = __builtin_amdgcn_cvt_pk_fp8_f32(a.z, a.w, w0, true);
        int w1 = __builtin_amdgcn_cvt_pk_fp8_f32(b.x, b.y, 0, false);
        w1     = __builtin_amdgcn_cvt_pk_fp8_f32(b.z, b.w, w1, true);
        uint2 o; o.x = (unsigned)w0; o.y = (unsigned)w1;
        *(uint2*)(ftab + (size_t)n * FEAT + q * 8) = o;
        float* orow = out + (size_t)n * 256 + q * 8;
        __builtin_nontemporal_store(a, (vfloat4*)orow);
        __builtin_nontemporal_store(b, (vfloat4*)(orow + 4));
    }
    if (t <= E) {
        int a = (t == 0) ? -1 : edge_dst[t - 1];
        int b = (t == E) ? N  : edge_dst[t];
        for (int n = a + 1; n <= b; ++n) row_start[n] = t;
    }
}

// One wave per 2 contiguous nodes, both processed with ALL loads in flight
// before any decode: 8 clamped edge-index loads -> 8 gathers (uint2 fp8 rows)
// -> decode/reduce/write A, then B. Hot path deg<=32; serial fallback beyond.
// eg = lane>>3 (edge slot), fq = lane&7 (8B = 8 fp8 dims).
template<int IS_HOP2>
__global__ void __launch_bounds__(256) hop(
        const unsigned char* __restrict__ table,
        const int* __restrict__ edge_src,
        const int* __restrict__ row_start,
        float* __restrict__ out,
        unsigned char* __restrict__ agg1t,
        int N, int E) {
    int wid = (blockIdx.x * blockDim.x + threadIdx.x) >> 6;
    int lane = threadIdx.x & 63;
    int eg = lane >> 3;
    int fq = lane & 7;
    int base = wid * 2;
    if (base >= N) return;

    int rs0 = row_start[base];
    int rs1 = row_start[base + 1];
    int i2 = (base + 2 <= N) ? (base + 2) : N;
    int rs2 = row_start[i2];
    bool twoB = (base + 1) < N;

    // caps keep clamped loads inside each node's own edge rows (dedup lines)
    int capA = (rs1 - 1 > rs0) ? (rs1 - 1) : ((rs0 < E - 1) ? rs0 : E - 1);
    int capB = (rs2 - 1 > rs1) ? (rs2 - 1) : ((rs1 < E - 1) ? rs1 : E - 1);

    int  idxA[4], idxB[4];
    bool vA[4],  vB[4];
    #pragma unroll
    for (int b = 0; b < 4; ++b) {
        int ia = rs0 + eg + 8 * b;
        vA[b] = ia < rs1;
        idxA[b] = edge_src[vA[b] ? ia : capA];
        int ib = rs1 + eg + 8 * b;
        vB[b] = twoB && (ib < rs2);
        idxB[b] = edge_src[vB[b] ? ib : capB];
    }
    uint2 pA[4], pB[4];
    #pragma unroll
    for (int b = 0; b < 4; ++b) {
        pA[b] = *(const uint2*)(table + (size_t)idxA[b] * FEAT + fq * 8);
        pB[b] = *(const uint2*)(table + (size_t)idxB[b] * FEAT + fq * 8);
    }

    // ---- node A ----
    {
        int n = base;
        vfloat2 a0 = {0.f,0.f}, a1 = {0.f,0.f}, a2 = {0.f,0.f}, a3 = {0.f,0.f};
        #pragma unroll
        for (int b = 0; b < 4; ++b) {
            uint2 p = pA[b];
            if (!vA[b]) { p.x = 0u; p.y = 0u; }
            ACCP(p);
        }
        for (int i = rs0 + eg + 32; i < rs1; i += 8) {   // rare deg>32 tail
            int sidx = edge_src[i];
            uint2 p = *(const uint2*)(table + (size_t)sidx * FEAT + fq * 8);
            ACCP(p);
        }
        #pragma unroll
        for (int m = 8; m <= 32; m <<= 1) {
            a0.x += __shfl_xor(a0.x, m, 64); a0.y += __shfl_xor(a0.y, m, 64);
            a1.x += __shfl_xor(a1.x, m, 64); a1.y += __shfl_xor(a1.y, m, 64);
            a2.x += __shfl_xor(a2.x, m, 64); a2.y += __shfl_xor(a2.y, m, 64);
            a3.x += __shfl_xor(a3.x, m, 64); a3.y += __shfl_xor(a3.y, m, 64);
        }
        float inv = 1.0f / (float)((rs1 - rs0) > 0 ? (rs1 - rs0) : 1);
        a0 *= inv; a1 *= inv; a2 *= inv; a3 *= inv;

        float* orow = out + (size_t)n * 256;
        vfloat4 v0 = {a0.x, a0.y, a1.x, a1.y};
        vfloat4 v1 = {a2.x, a2.y, a3.x, a3.y};
        if (IS_HOP2) {
            if (eg == 0) {
                __builtin_nontemporal_store(v0, (vfloat4*)(orow + 192 + fq * 8));
                __builtin_nontemporal_store(v1, (vfloat4*)(orow + 192 + fq * 8 + 4));
            }
        } else {
            if (eg == 0) {
                __builtin_nontemporal_store(v0, (vfloat4*)(orow + 64 + fq * 8));
                __builtin_nontemporal_store(v1, (vfloat4*)(orow + 64 + fq * 8 + 4));
            } else if (eg == 1) {
                __builtin_nontemporal_store(v0, (vfloat4*)(orow + 128 + fq * 8));
                __builtin_nontemporal_store(v1, (vfloat4*)(orow + 128 + fq * 8 + 4));
            } else if (eg == 2) {
                int w0 = __builtin_amdgcn_cvt_pk_fp8_f32(a0.x, a0.y, 0, false);
                w0     = __builtin_amdgcn_cvt_pk_fp8_f32(a1.x, a1.y, w0, true);
                int w1 = __builtin_amdgcn_cvt_pk_fp8_f32(a2.x, a2.y, 0, false);
                w1     = __builtin_amdgcn_cvt_pk_fp8_f32(a3.x, a3.y, w1, true);
                uint2 pk; pk.x = (unsigned)w0; pk.y = (unsigned)w1;
                *(uint2*)(agg1t + (size_t)n * FEAT + fq * 8) = pk;
            }
        }
    }

    // ---- node B ----
    if (twoB) {
        int n = base + 1;
        vfloat2 a0 = {0.f,0.f}, a1 = {0.f,0.f}, a2 = {0.f,0.f}, a3 = {0.f,0.f};
        #pragma unroll
        for (int b = 0; b < 4; ++b) {
            uint2 p = pB[b];
            if (!vB[b]) { p.x = 0u; p.y = 0u; }
            ACCP(p);
        }
        for (int i = rs1 + eg + 32; i < rs2; i += 8) {   // rare deg>32 tail
            int sidx = edge_src[i];
            uint2 p = *(const uint2*)(table + (size_t)sidx * FEAT + fq * 8);
            ACCP(p);
        }
        #pragma unroll
        for (int m = 8; m <= 32; m <<= 1) {
            a0.x += __shfl_xor(a0.x, m, 64); a0.y += __shfl_xor(a0.y, m, 64);
            a1.x += __shfl_xor(a1.x, m, 64); a1.y += __shfl_xor(a1.y, m, 64);
            a2.x += __shfl_xor(a2.x, m, 64); a2.y += __shfl_xor(a2.y, m, 64);
            a3.x += __shfl_xor(a3.x, m, 64); a3.y += __shfl_xor(a3.y, m, 64);
        }
        float inv = 1.0f / (float)((rs2 - rs1) > 0 ? (rs2 - rs1) : 1);
        a0 *= inv; a1 *= inv; a2 *= inv; a3 *= inv;

        float* orow = out + (size_t)n * 256;
        vfloat4 v0 = {a0.x, a0.y, a1.x, a1.y};
        vfloat4 v1 = {a2.x, a2.y, a3.x, a3.y};
        if (IS_HOP2) {
            if (eg == 0) {
                __builtin_nontemporal_store(v0, (vfloat4*)(orow + 192 + fq * 8));
                __builtin_nontemporal_store(v1, (vfloat4*)(orow + 192 + fq * 8 + 4));
            }
        } else {
            if (eg == 0) {
                __builtin_nontemporal_store(v0, (vfloat4*)(orow + 64 + fq * 8));
                __builtin_nontemporal_store(v1, (vfloat4*)(orow + 64 + fq * 8 + 4));
            } else if (eg == 1) {
                __builtin_nontemporal_store(v0, (vfloat4*)(orow + 128 + fq * 8));
                __builtin_nontemporal_store(v1, (vfloat4*)(orow + 128 + fq * 8 + 4));
            } else if (eg == 2) {
                int w0 = __builtin_amdgcn_cvt_pk_fp8_f32(a0.x, a0.y, 0, false);
                w0     = __builtin_amdgcn_cvt_pk_fp8_f32(a1.x, a1.y, w0, true);
                int w1 = __builtin_amdgcn_cvt_pk_fp8_f32(a2.x, a2.y, 0, false);
                w1     = __builtin_amdgcn_cvt_pk_fp8_f32(a3.x, a3.y, w1, true);
                uint2 pk; pk.x = (unsigned)w0; pk.y = (unsigned)w1;
                *(uint2*)(agg1t + (size_t)n * FEAT + fq * 8) = pk;
            }
        }
    }
}

extern "C" void kernel_launch(void* const* d_in, const int* in_sizes, int n_in,
                              void* d_out, int out_size, void* d_ws, size_t ws_size,
                              hipStream_t stream) {
    const float* feat     = (const float*)d_in[0];
    const int*   edge_src = (const int*)d_in[1];
    const int*   edge_dst = (const int*)d_in[2];
    float*       out      = (float*)d_out;

    int N = in_sizes[0] / FEAT;
    int E = in_sizes[1];

    // ws: ftab [N*64] fp8, agg1t [N*64] fp8, row_start [N+1] int
    unsigned char* ftab  = (unsigned char*)d_ws;
    unsigned char* agg1t = ftab + (size_t)N * FEAT;
    int* row_start       = (int*)(agg1t + (size_t)N * FEAT);

    int prep_blocks = (E + 1 + 255) / 256;           // covers t<=E and t<N*8
    prep<<<prep_blocks, 256, 0, stream>>>(feat, edge_dst, ftab, row_start, out, N, E);

    int waves  = (N + 1) / 2;
    int blocks = (waves + 3) / 4;                    // 4 waves per 256-thread block
    hop<0><<<blocks, 256, 0, stream>>>(ftab,  edge_src, row_start, out, agg1t, N, E);
    hop<1><<<blocks, 256, 0, stream>>>(agg1t, edge_src, row_start, out, agg1t, N, E);
}

// Round 14
// 41.732 us; speedup vs baseline: 1.2173x; 1.1352x over previous
//
#include <hip/hip_runtime.h>

#define FEAT 64

typedef float vfloat2 __attribute__((ext_vector_type(2)));
typedef float vfloat4 __attribute__((ext_vector_type(4)));

// Decode a uint2 (8 fp8 e4m3) into 4 packed vfloat2 accumulators (v_pk_add_f32).
#define ACCP(P)                                                     \
    {                                                               \
        a0 += __builtin_amdgcn_cvt_pk_f32_fp8((int)(P).x, false);   \
        a1 += __builtin_amdgcn_cvt_pk_f32_fp8((int)(P).x, true);    \
        a2 += __builtin_amdgcn_cvt_pk_f32_fp8((int)(P).y, false);   \
        a3 += __builtin_amdgcn_cvt_pk_f32_fp8((int)(P).y, true);    \
    }

// Fused prep: feat -> fp8 table + out[:,0:64] f32 (NT); CSR rowptr via
// adjacent-pair scan of the sorted edge_dst (coalesced, no binary search).
__global__ void prep(const float* __restrict__ feat,
                     const int* __restrict__ edge_dst,
                     unsigned char* __restrict__ ftab,    // [N][64] fp8
                     int* __restrict__ row_start,         // [N+1]
                     float* __restrict__ out, int N, int E) {
    int t = blockIdx.x * blockDim.x + threadIdx.x;
    if (t < N * 8) {
        int n = t >> 3, q = t & 7;
        const float* srcp = feat + (size_t)n * FEAT + q * 8;
        vfloat4 a = __builtin_nontemporal_load((const vfloat4*)srcp);
        vfloat4 b = __builtin_nontemporal_load((const vfloat4*)(srcp + 4));
        int w0 = __builtin_amdgcn_cvt_pk_fp8_f32(a.x, a.y, 0, false);
        w0     = __builtin_amdgcn_cvt_pk_fp8_f32(a.z, a.w, w0, true);
        int w1 = __builtin_amdgcn_cvt_pk_fp8_f32(b.x, b.y, 0, false);
        w1     = __builtin_amdgcn_cvt_pk_fp8_f32(b.z, b.w, w1, true);
        uint2 o; o.x = (unsigned)w0; o.y = (unsigned)w1;
        *(uint2*)(ftab + (size_t)n * FEAT + q * 8) = o;
        float* orow = out + (size_t)n * 256 + q * 8;
        __builtin_nontemporal_store(a, (vfloat4*)orow);
        __builtin_nontemporal_store(b, (vfloat4*)(orow + 4));
    }
    if (t <= E) {
        int a = (t == 0) ? -1 : edge_dst[t - 1];
        int b = (t == E) ? N  : edge_dst[t];
        for (int n = a + 1; n <= b; ++n) row_start[n] = t;
    }
}

// Wave = 8 nodes; lane = (node slot ns = lane>>3) x (dim octet fq = lane&7).
// Each lane serially accumulates its 8 dims over its node's edges in 4-edge
// batches (4 independent idx loads -> 4 independent gathers). NO cross-lane
// reduction at all; every lane writes its own output dims.
// IS_HOP2==0: table=ftab; writes out[:,64:128] + out[:,128:192] (agg1 dup,
//             == agg2[:,0:64]) f32 NT, and agg1 fp8 -> agg1t.
// IS_HOP2==1: table=agg1t; writes out[:,192:256] f32 NT.
template<int IS_HOP2>
__global__ void __launch_bounds__(256) hop(
        const unsigned char* __restrict__ table,
        const int* __restrict__ edge_src,
        const int* __restrict__ row_start,
        float* __restrict__ out,
        unsigned char* __restrict__ agg1t,
        int N) {
    int wid = (blockIdx.x * blockDim.x + threadIdx.x) >> 6;
    int lane = threadIdx.x & 63;
    int ns = lane >> 3;
    int fq = lane & 7;
    int n = wid * 8 + ns;
    bool act = n < N;
    int nc = act ? n : (N - 1);
    int rs = row_start[nc];
    int re = row_start[nc + 1];
    if (!act) re = rs;

    vfloat2 a0 = {0.f,0.f}, a1 = {0.f,0.f}, a2 = {0.f,0.f}, a3 = {0.f,0.f};
    int k = rs;
    for (; k + 4 <= re; k += 4) {
        int i0 = edge_src[k];
        int i1 = edge_src[k + 1];
        int i2 = edge_src[k + 2];
        int i3 = edge_src[k + 3];
        uint2 p0 = *(const uint2*)(table + (size_t)i0 * FEAT + fq * 8);
        uint2 p1 = *(const uint2*)(table + (size_t)i1 * FEAT + fq * 8);
        uint2 p2 = *(const uint2*)(table + (size_t)i2 * FEAT + fq * 8);
        uint2 p3 = *(const uint2*)(table + (size_t)i3 * FEAT + fq * 8);
        ACCP(p0); ACCP(p1); ACCP(p2); ACCP(p3);
    }
    for (; k < re; ++k) {
        int i0 = edge_src[k];
        uint2 p0 = *(const uint2*)(table + (size_t)i0 * FEAT + fq * 8);
        ACCP(p0);
    }

    float inv = 1.0f / (float)((re - rs) > 0 ? (re - rs) : 1);
    a0 *= inv; a1 *= inv; a2 *= inv; a3 *= inv;

    if (act) {
        float* orow = out + (size_t)n * 256;
        vfloat4 v0 = {a0.x, a0.y, a1.x, a1.y};
        vfloat4 v1 = {a2.x, a2.y, a3.x, a3.y};
        if (IS_HOP2) {
            __builtin_nontemporal_store(v0, (vfloat4*)(orow + 192 + fq * 8));
            __builtin_nontemporal_store(v1, (vfloat4*)(orow + 192 + fq * 8 + 4));
        } else {
            __builtin_nontemporal_store(v0, (vfloat4*)(orow + 64 + fq * 8));
            __builtin_nontemporal_store(v1, (vfloat4*)(orow + 64 + fq * 8 + 4));
            __builtin_nontemporal_store(v0, (vfloat4*)(orow + 128 + fq * 8));
            __builtin_nontemporal_store(v1, (vfloat4*)(orow + 128 + fq * 8 + 4));
            int w0 = __builtin_amdgcn_cvt_pk_fp8_f32(a0.x, a0.y, 0, false);
            w0     = __builtin_amdgcn_cvt_pk_fp8_f32(a1.x, a1.y, w0, true);
            int w1 = __builtin_amdgcn_cvt_pk_fp8_f32(a2.x, a2.y, 0, false);
            w1     = __builtin_amdgcn_cvt_pk_fp8_f32(a3.x, a3.y, w1, true);
            uint2 pk; pk.x = (unsigned)w0; pk.y = (unsigned)w1;
            *(uint2*)(agg1t + (size_t)n * FEAT + fq * 8) = pk;
        }
    }
}

extern "C" void kernel_launch(void* const* d_in, const int* in_sizes, int n_in,
                              void* d_out, int out_size, void* d_ws, size_t ws_size,
                              hipStream_t stream) {
    const float* feat     = (const float*)d_in[0];
    const int*   edge_src = (const int*)d_in[1];
    const int*   edge_dst = (const int*)d_in[2];
    float*       out      = (float*)d_out;

    int N = in_sizes[0] / FEAT;
    int E = in_sizes[1];

    // ws: ftab [N*64] fp8, agg1t [N*64] fp8, row_start [N+1] int
    unsigned char* ftab  = (unsigned char*)d_ws;
    unsigned char* agg1t = ftab + (size_t)N * FEAT;
    int* row_start       = (int*)(agg1t + (size_t)N * FEAT);

    int prep_blocks = (E + 1 + 255) / 256;           // covers t<=E and t<N*8
    prep<<<prep_blocks, 256, 0, stream>>>(feat, edge_dst, ftab, row_start, out, N, E);

    int waves  = (N + 7) / 8;
    int blocks = (waves + 3) / 4;                    // 4 waves per 256-thread block
    hop<0><<<blocks, 256, 0, stream>>>(ftab,  edge_src, row_start, out, agg1t, N);
    hop<1><<<blocks, 256, 0, stream>>>(agg1t, edge_src, row_start, out, agg1t, N);
}

// Round 15
// 39.353 us; speedup vs baseline: 1.2909x; 1.0604x over previous
//
#include <hip/hip_runtime.h>

#define FEAT 64

typedef float vfloat2 __attribute__((ext_vector_type(2)));
typedef float vfloat4 __attribute__((ext_vector_type(4)));

// Decode a uint2 (8 fp8 e4m3) into 4 packed vfloat2 accumulators (v_pk_add_f32).
#define ACCP(P)                                                     \
    {                                                               \
        a0 += __builtin_amdgcn_cvt_pk_f32_fp8((int)(P).x, false);   \
        a1 += __builtin_amdgcn_cvt_pk_f32_fp8((int)(P).x, true);    \
        a2 += __builtin_amdgcn_cvt_pk_f32_fp8((int)(P).y, false);   \
        a3 += __builtin_amdgcn_cvt_pk_f32_fp8((int)(P).y, true);    \
    }

// Fused prep: feat -> fp8 table + out[:,0:64] f32 (NT); CSR rowptr via
// adjacent-pair scan of the sorted edge_dst (coalesced, no binary search).
__global__ void prep(const float* __restrict__ feat,
                     const int* __restrict__ edge_dst,
                     unsigned char* __restrict__ ftab,    // [N][64] fp8
                     int* __restrict__ row_start,         // [N+1]
                     float* __restrict__ out, int N, int E) {
    int t = blockIdx.x * blockDim.x + threadIdx.x;
    if (t < N * 8) {
        int n = t >> 3, q = t & 7;
        const float* srcp = feat + (size_t)n * FEAT + q * 8;
        vfloat4 a = __builtin_nontemporal_load((const vfloat4*)srcp);
        vfloat4 b = __builtin_nontemporal_load((const vfloat4*)(srcp + 4));
        int w0 = __builtin_amdgcn_cvt_pk_fp8_f32(a.x, a.y, 0, false);
        w0     = __builtin_amdgcn_cvt_pk_fp8_f32(a.z, a.w, w0, true);
        int w1 = __builtin_amdgcn_cvt_pk_fp8_f32(b.x, b.y, 0, false);
        w1     = __builtin_amdgcn_cvt_pk_fp8_f32(b.z, b.w, w1, true);
        uint2 o; o.x = (unsigned)w0; o.y = (unsigned)w1;
        *(uint2*)(ftab + (size_t)n * FEAT + q * 8) = o;
        float* orow = out + (size_t)n * 256 + q * 8;
        __builtin_nontemporal_store(a, (vfloat4*)orow);
        __builtin_nontemporal_store(b, (vfloat4*)(orow + 4));
    }
    if (t <= E) {
        int a = (t == 0) ? -1 : edge_dst[t - 1];
        int b = (t == E) ? N  : edge_dst[t];
        for (int n = a + 1; n <= b; ++n) row_start[n] = t;
    }
}

// Wave = 8 nodes; lane = (node slot ns = lane>>3) x (dim octet fq = lane&7).
// Each lane serially accumulates its 8 dims over its node's edges.
// Inner loop: 8-edge super-batches — 8 independent idx loads, then 8
// independent gathers, all in flight before any decode (2 latency rounds
// per 8 edges). Tail: one 4-batch + scalars. No cross-lane reduction.
// IS_HOP2==0: table=ftab; writes out[:,64:128] + out[:,128:192] (agg1 dup,
//             == agg2[:,0:64]) f32 NT, and agg1 fp8 -> agg1t.
// IS_HOP2==1: table=agg1t; writes out[:,192:256] f32 NT.
template<int IS_HOP2>
__global__ void __launch_bounds__(256) hop(
        const unsigned char* __restrict__ table,
        const int* __restrict__ edge_src,
        const int* __restrict__ row_start,
        float* __restrict__ out,
        unsigned char* __restrict__ agg1t,
        int N) {
    int wid = (blockIdx.x * blockDim.x + threadIdx.x) >> 6;
    int lane = threadIdx.x & 63;
    int ns = lane >> 3;
    int fq = lane & 7;
    int n = wid * 8 + ns;
    bool act = n < N;
    int nc = act ? n : (N - 1);
    int rs = row_start[nc];
    int re = row_start[nc + 1];
    if (!act) re = rs;

    vfloat2 a0 = {0.f,0.f}, a1 = {0.f,0.f}, a2 = {0.f,0.f}, a3 = {0.f,0.f};
    int k = rs;
    for (; k + 8 <= re; k += 8) {
        int i0 = edge_src[k];
        int i1 = edge_src[k + 1];
        int i2 = edge_src[k + 2];
        int i3 = edge_src[k + 3];
        int i4 = edge_src[k + 4];
        int i5 = edge_src[k + 5];
        int i6 = edge_src[k + 6];
        int i7 = edge_src[k + 7];
        uint2 p0 = *(const uint2*)(table + (size_t)i0 * FEAT + fq * 8);
        uint2 p1 = *(const uint2*)(table + (size_t)i1 * FEAT + fq * 8);
        uint2 p2 = *(const uint2*)(table + (size_t)i2 * FEAT + fq * 8);
        uint2 p3 = *(const uint2*)(table + (size_t)i3 * FEAT + fq * 8);
        uint2 p4 = *(const uint2*)(table + (size_t)i4 * FEAT + fq * 8);
        uint2 p5 = *(const uint2*)(table + (size_t)i5 * FEAT + fq * 8);
        uint2 p6 = *(const uint2*)(table + (size_t)i6 * FEAT + fq * 8);
        uint2 p7 = *(const uint2*)(table + (size_t)i7 * FEAT + fq * 8);
        ACCP(p0); ACCP(p1); ACCP(p2); ACCP(p3);
        ACCP(p4); ACCP(p5); ACCP(p6); ACCP(p7);
    }
    if (k + 4 <= re) {
        int i0 = edge_src[k];
        int i1 = edge_src[k + 1];
        int i2 = edge_src[k + 2];
        int i3 = edge_src[k + 3];
        uint2 p0 = *(const uint2*)(table + (size_t)i0 * FEAT + fq * 8);
        uint2 p1 = *(const uint2*)(table + (size_t)i1 * FEAT + fq * 8);
        uint2 p2 = *(const uint2*)(table + (size_t)i2 * FEAT + fq * 8);
        uint2 p3 = *(const uint2*)(table + (size_t)i3 * FEAT + fq * 8);
        ACCP(p0); ACCP(p1); ACCP(p2); ACCP(p3);
        k += 4;
    }
    for (; k < re; ++k) {
        int i0 = edge_src[k];
        uint2 p0 = *(const uint2*)(table + (size_t)i0 * FEAT + fq * 8);
        ACCP(p0);
    }

    float inv = 1.0f / (float)((re - rs) > 0 ? (re - rs) : 1);
    a0 *= inv; a1 *= inv; a2 *= inv; a3 *= inv;

    if (act) {
        float* orow = out + (size_t)n * 256;
        vfloat4 v0 = {a0.x, a0.y, a1.x, a1.y};
        vfloat4 v1 = {a2.x, a2.y, a3.x, a3.y};
        if (IS_HOP2) {
            __builtin_nontemporal_store(v0, (vfloat4*)(orow + 192 + fq * 8));
            __builtin_nontemporal_store(v1, (vfloat4*)(orow + 192 + fq * 8 + 4));
        } else {
            __builtin_nontemporal_store(v0, (vfloat4*)(orow + 64 + fq * 8));
            __builtin_nontemporal_store(v1, (vfloat4*)(orow + 64 + fq * 8 + 4));
            __builtin_nontemporal_store(v0, (vfloat4*)(orow + 128 + fq * 8));
            __builtin_nontemporal_store(v1, (vfloat4*)(orow + 128 + fq * 8 + 4));
            int w0 = __builtin_amdgcn_cvt_pk_fp8_f32(a0.x, a0.y, 0, false);
            w0     = __builtin_amdgcn_cvt_pk_fp8_f32(a1.x, a1.y, w0, true);
            int w1 = __builtin_amdgcn_cvt_pk_fp8_f32(a2.x, a2.y, 0, false);
            w1     = __builtin_amdgcn_cvt_pk_fp8_f32(a3.x, a3.y, w1, true);
            uint2 pk; pk.x = (unsigned)w0; pk.y = (unsigned)w1;
            *(uint2*)(agg1t + (size_t)n * FEAT + fq * 8) = pk;
        }
    }
}

extern "C" void kernel_launch(void* const* d_in, const int* in_sizes, int n_in,
                              void* d_out, int out_size, void* d_ws, size_t ws_size,
                              hipStream_t stream) {
    const float* feat     = (const float*)d_in[0];
    const int*   edge_src = (const int*)d_in[1];
    const int*   edge_dst = (const int*)d_in[2];
    float*       out      = (float*)d_out;

    int N = in_sizes[0] / FEAT;
    int E = in_sizes[1];

    // ws: ftab [N*64] fp8, agg1t [N*64] fp8, row_start [N+1] int
    unsigned char* ftab  = (unsigned char*)d_ws;
    unsigned char* agg1t = ftab + (size_t)N * FEAT;
    int* row_start       = (int*)(agg1t + (size_t)N * FEAT);

    int prep_blocks = (E + 1 + 255) / 256;           // covers t<=E and t<N*8
    prep<<<prep_blocks, 256, 0, stream>>>(feat, edge_dst, ftab, row_start, out, N, E);

    int waves  = (N + 7) / 8;
    int blocks = (waves + 3) / 4;                    // 4 waves per 256-thread block
    hop<0><<<blocks, 256, 0, stream>>>(ftab,  edge_src, row_start, out, agg1t, N);
    hop<1><<<blocks, 256, 0, stream>>>(agg1t, edge_src, row_start, out, agg1t, N);
}